// Round 21
// baseline (1161.095 us; speedup 1.0000x reference)
//
#include <hip/hip_runtime.h>
#include <cstdint>
#include <cstddef>

#define NN 50000
#define INDIM 32
#define HIDD 128
#define OUTD 10
#define KK 5
#define EK 400000
#define GG 500
#define CAP 40   // max node degree per slice; Poisson(mean 8) -> overflow ~1e-15
#define NB 782   // (NN+63)/64 row tiles

typedef __attribute__((ext_vector_type(4))) float float4v;
typedef __attribute__((ext_vector_type(4))) unsigned int uint4v;
typedef unsigned short ushort;
typedef _Float16 half_t;
typedef __attribute__((ext_vector_type(4))) _Float16 half4v;
typedef __attribute__((ext_vector_type(8))) _Float16 half8v;

static __device__ __forceinline__ float w_unpack(unsigned int u) {
    unsigned short hb = (unsigned short)(u >> 16);
    half_t h;
    __builtin_memcpy(&h, &hb, sizeof(h));
    return (float)h;
}

// ---------- fused degree-count + capacity-CSR scatter (uint: idx | w<<16) ---
__global__ void k_scatter(const int* __restrict__ srcA, const int* __restrict__ dstA,
                          int* __restrict__ cnt, unsigned int* __restrict__ colw) {
    int e = blockIdx.x * blockDim.x + threadIdx.x;
    if (e >= KK * EK) return;
    int s = e / EK;
    int sv = srcA[e], dv = dstA[e];
    int pos = atomicAdd(&cnt[s * NN + dv], 1);
    if (pos < CAP) colw[(size_t)(s * NN + dv) * CAP + pos] = (unsigned int)sv;
}

// dinv = 1/sqrt(deg+1)
__global__ void k_dinv(const int* __restrict__ cnt, float* __restrict__ dinv) {
    int i = blockIdx.x * blockDim.x + threadIdx.x;
    if (i >= KK * NN) return;
    float d = (float)(cnt[i] + 1);
    dinv[i] = 1.0f / sqrtf(d);
}

// ---------- pack per-edge weight dinv[s][src] into high 16 bits of colw -----
// Pads slots [cn, CAP) with {self_idx, w=+0.0h}: gather loop needs no masks
// (dummy slots contribute 0; self row is cache-hot from the self term).
__global__ void k_edgew(const int* __restrict__ cnt, const float* __restrict__ dinv,
                        unsigned int* __restrict__ colw) {
    int i = blockIdx.x * blockDim.x + threadIdx.x;
    if (i >= KK * NN) return;
    int s = i / NN;
    int node = i - s * NN;
    const float* dvs = dinv + s * NN;
    int cn = cnt[i];
    cn = cn < CAP ? cn : CAP;
    unsigned int* cp = colw + (size_t)i * CAP;
    for (int p = 0; p < cn; ++p) {
        unsigned int u = cp[p] & 0xffffu;
        half_t w = (half_t)dvs[u];
        unsigned short wb;
        __builtin_memcpy(&wb, &w, sizeof(wb));
        cp[p] = u | ((unsigned int)wb << 16);
    }
    unsigned int dummy = (unsigned int)node;   // high 16 bits = 0 => w = +0.0
    for (int p = cn; p < CAP; ++p) cp[p] = dummy;
}

// ---------- weight transpose: in[m][j][c] -> out[m][c][j] ----------
__global__ void k_tr(const float* __restrict__ in, float* __restrict__ out,
                     int J, int C, int total) {
    int idx = blockIdx.x * blockDim.x + threadIdx.x;
    if (idx >= total) return;
    int jc = J * C;
    int m = idx / jc, rem = idx - m * jc;
    int j = rem / C, c = rem - j * C;
    out[m * jc + c * J + j] = in[idx];
}

// ---------- fused layer, 512-thread blocks, fp16 activations ----------------
// Instruction-diet: maskless gather (padded CSR) + b128 LDS reads in GEMM.
__global__ __launch_bounds__(512) void k_layer(const half_t* __restrict__ xh,
                                               const int* __restrict__ cnt,
                                               const unsigned int* __restrict__ colw,
                                               const float* __restrict__ dinv,
                                               const float* __restrict__ Wt,
                                               const float* __restrict__ conv_b,
                                               int lp1, half_t* __restrict__ out) {
    constexpr int LDA = HIDD + 4;  // 132 words: 16B-aligned rows and 4-word chunks
    __shared__ float At[64 * LDA];
    const int tid = threadIdx.x;
    const int r0 = blockIdx.x * 64;
    const int lane = tid & 63, wv = tid >> 6;        // wv in [0,8)
    const int half = lane >> 5, ln = lane & 31;
    const int hw = wv * 2 + half;                    // half-wave id in [0,16)
    const int tr = tid >> 5, tc = tid & 31;          // GEMM: 16 row-groups x 32 cols
    const int ra = tr * 4;
    const int cib = (lp1 - 1) * lp1 / 2;

    float acc[4][4];
#pragma unroll
    for (int q = 0; q < 4; ++q)
#pragma unroll
        for (int u = 0; u < 4; ++u) acc[q][u] = 0.f;

    for (int k = 1; k <= lp1; ++k) {
        const int s = k - 1, sN = s * NN, ci = cib + s;
        const float inv_k = 1.0f / (float)k;
        const half_t* Xin = xh + (size_t)(lp1 - k) * NN * HIDD;
        const float* dvs = dinv + sN;

        // ---- gather phase: 16 half-waves x 4 passes cover 64 rows ----
#pragma unroll 1
        for (int pass = 0; pass < 4; ++pass) {
            int lrow = pass * 16 + hw;
            int node = r0 + lrow;
            bool valid = node < NN;
            int nc = valid ? node : NN - 1;
            int cn = 0;
            if (valid) {
                cn = cnt[sN + node];
                cn = cn < CAP ? cn : CAP;
            }
            const unsigned int* cp = colw + (size_t)(sN + nc) * CAP;
            float dv = valid ? dvs[node] : 0.f;
            float hd = dv * inv_k;   // row coef; 0 for invalid rows kills garbage
            const half_t* Xb = Xin + ln * 4;
            // self term: (dinv^2/k)*x_v  ==  (x_v*dv)*hd
            float4v a = __builtin_convertvector(
                            *(const half4v*)(Xb + (size_t)nc * HIDD), float4v) * dv;

            int cnr = (cn + 3) & ~3;
            int cm = cnr;
            {   // shared instruction stream: bound = max over the wave's two halves
                int o = __shfl_xor(cnr, 32);
                cm = cm > o ? cm : o;
            }
            // maskless: slots [cn, CAP) hold {self_idx, w=0}
            uint4v cc = *(const uint4v*)(cp);
            for (int i = 0; i < cm; i += 4) {
                uint4v ccn = *(const uint4v*)(cp + i + 4);  // prefetch next
                int j0 = (int)(cc.x & 0xffffu);
                int j1 = (int)(cc.y & 0xffffu);
                int j2 = (int)(cc.z & 0xffffu);
                int j3 = (int)(cc.w & 0xffffu);
                half4v h0 = *(const half4v*)(Xb + (size_t)j0 * HIDD);
                half4v h1 = *(const half4v*)(Xb + (size_t)j1 * HIDD);
                half4v h2 = *(const half4v*)(Xb + (size_t)j2 * HIDD);
                half4v h3 = *(const half4v*)(Xb + (size_t)j3 * HIDD);
                float w0 = w_unpack(cc.x);
                float w1 = w_unpack(cc.y);
                float w2 = w_unpack(cc.z);
                float w3 = w_unpack(cc.w);
                a += __builtin_convertvector(h0, float4v) * w0
                   + __builtin_convertvector(h1, float4v) * w1
                   + __builtin_convertvector(h2, float4v) * w2
                   + __builtin_convertvector(h3, float4v) * w3;
                cc = ccn;
            }
            *(float4v*)(&At[lrow * LDA + ln * 4]) = a * hd;
        }
        __syncthreads();

        // ---- GEMM phase: acc += At @ Wt[ci]; b128 LDS reads serve 4 c-iters --
        const float* wp = Wt + (size_t)ci * HIDD * HIDD + tc * 4;
#pragma unroll 2
        for (int c0 = 0; c0 < HIDD; c0 += 4) {
            float4v A0 = *(const float4v*)(&At[(ra + 0) * LDA + c0]);
            float4v A1 = *(const float4v*)(&At[(ra + 1) * LDA + c0]);
            float4v A2 = *(const float4v*)(&At[(ra + 2) * LDA + c0]);
            float4v A3 = *(const float4v*)(&At[(ra + 3) * LDA + c0]);
#pragma unroll
            for (int cc2 = 0; cc2 < 4; ++cc2) {
                float4v w0 = *(const float4v*)(wp + (size_t)(c0 + cc2) * HIDD);
#pragma unroll
                for (int u = 0; u < 4; ++u) {
                    acc[0][u] += A0[cc2] * w0[u];
                    acc[1][u] += A1[cc2] * w0[u];
                    acc[2][u] += A2[cc2] * w0[u];
                    acc[3][u] += A3[cc2] * w0[u];
                }
            }
        }
        __syncthreads();   // before next k's gather overwrites At
    }

    // ---- epilogue: summed bias, relu, quantize to fp16, single write ----
    float bj[4];
#pragma unroll
    for (int u = 0; u < 4; ++u) bj[u] = 0.f;
    for (int k = 1; k <= lp1; ++k) {
        const float* bp = conv_b + (size_t)(cib + k - 1) * HIDD + tc * 4;
        float inv_k = 1.0f / (float)k;
#pragma unroll
        for (int u = 0; u < 4; ++u) bj[u] += bp[u] * inv_k;
    }
#pragma unroll
    for (int q = 0; q < 4; ++q) {
        int gr = r0 + ra + q;
        if (gr >= NN) continue;
        half_t* op = out + (size_t)gr * HIDD + tc * 4;
        half4v o0;
#pragma unroll
        for (int u = 0; u < 4; ++u) {
            float v = acc[q][u] + bj[u];
            o0[u] = (half_t)(v > 0.f ? v : 0.f);
        }
        *(half4v*)(op) = o0;
    }
}

// ---------- embedding GEMM (K=32): xh0 = fp16( x @ emb_W.T + emb_b ) --------
__global__ __launch_bounds__(256) void k_emb(const float* __restrict__ A,
                                             const float* __restrict__ Wt,
                                             const float* __restrict__ bias,
                                             half_t* __restrict__ out) {
    constexpr int KD = INDIM, LDA = KD + 4;
    __shared__ float At[64 * LDA];
    int tid = threadIdx.x;
    int r0 = blockIdx.x * 64;

    constexpr int F4R = KD / 4;
    constexpr int PER = 64 * F4R / 256;
#pragma unroll
    for (int t = 0; t < PER; ++t) {
        int f4 = tid + t * 256;
        int row = f4 / F4R, c4 = (f4 - row * F4R) * 4;
        float4v v = {0.f, 0.f, 0.f, 0.f};
        int gr = r0 + row;
        if (gr < NN) v = *(const float4v*)(A + (size_t)gr * KD + c4);
        *(float4v*)(At + row * LDA + c4) = v;
    }
    __syncthreads();

    int tr = tid >> 4, tc = tid & 15;
    int ra = tr * 4;
    float acc[4][8];
#pragma unroll
    for (int q = 0; q < 4; ++q)
#pragma unroll
        for (int u = 0; u < 8; ++u) acc[q][u] = 0.f;

    const float* wp = Wt + tc * 8;
#pragma unroll
    for (int c = 0; c < KD; ++c) {
        float4v w0 = *(const float4v*)(wp + (size_t)c * HIDD);
        float4v w1 = *(const float4v*)(wp + (size_t)c * HIDD + 4);
        float a0 = At[(ra + 0) * LDA + c];
        float a1 = At[(ra + 1) * LDA + c];
        float a2 = At[(ra + 2) * LDA + c];
        float a3 = At[(ra + 3) * LDA + c];
#pragma unroll
        for (int u = 0; u < 4; ++u) {
            acc[0][u] += a0 * w0[u];  acc[0][u + 4] += a0 * w1[u];
            acc[1][u] += a1 * w0[u];  acc[1][u + 4] += a1 * w1[u];
            acc[2][u] += a2 * w0[u];  acc[2][u + 4] += a2 * w1[u];
            acc[3][u] += a3 * w0[u];  acc[3][u + 4] += a3 * w1[u];
        }
    }

#pragma unroll
    for (int q = 0; q < 4; ++q) {
        int gr = r0 + ra + q;
        if (gr >= NN) continue;
        half_t* op = out + (size_t)gr * HIDD + tc * 8;
        half8v o;
#pragma unroll
        for (int u = 0; u < 8; ++u)
            o[u] = (half_t)(acc[q][u] + bias[tc * 8 + u]);
        *(half8v*)(op) = o;
    }
}

// ---------- pooling (100 consecutive nodes/graph, fp16 in) + 2-layer MLP ----
__global__ __launch_bounds__(256) void k_poolf(const half_t* __restrict__ h,
                                               const float* __restrict__ r1W,
                                               const float* __restrict__ r1b,
                                               const float* __restrict__ r2W,
                                               const float* __restrict__ r2b,
                                               float* __restrict__ out) {
    __shared__ float pooled[384];
    __shared__ float hid[192];
    int g = blockIdx.x, tid = threadIdx.x;
    if (tid < 128) {
        const half_t* hp = h + (size_t)g * 100 * HIDD + tid;
        float s = 0.f, m = -3.0e38f;
        for (int n = 0; n < 100; ++n) {
            float v = (float)hp[(size_t)n * HIDD];
            s += v;
            m = fmaxf(m, v);
        }
        pooled[tid] = s;
        pooled[128 + tid] = m;
        pooled[256 + tid] = s * 0.01f;
    }
    __syncthreads();
    if (tid < 192) {
        float acc = r1b[tid];
        const float* w = r1W + (size_t)tid * 384;
        for (int c = 0; c < 384; ++c) acc += pooled[c] * w[c];
        hid[tid] = acc >= 0.f ? acc : 0.01f * acc;
    }
    __syncthreads();
    if (tid < OUTD) {
        float acc = r2b[tid];
        const float* w = r2W + (size_t)tid * 192;
        for (int c = 0; c < 192; ++c) acc += hid[c] * w[c];
        out[g * OUTD + tid] = acc;
    }
}

extern "C" void kernel_launch(void* const* d_in, const int* in_sizes, int n_in,
                              void* d_out, int out_size, void* d_ws, size_t ws_size,
                              hipStream_t stream) {
    const float* x      = (const float*)d_in[0];
    const int*   kei    = (const int*)d_in[1];
    const float* emb_W  = (const float*)d_in[4];
    const float* emb_b  = (const float*)d_in[5];
    const float* conv_W = (const float*)d_in[6];
    const float* conv_b = (const float*)d_in[7];
    const float* r1W    = (const float*)d_in[8];
    const float* r1b    = (const float*)d_in[9];
    const float* r2W    = (const float*)d_in[10];
    const float* r2b    = (const float*)d_in[11];

    const int* srcA = kei;            // row 0 of (2, K*E_K)
    const int* dstA = kei + KK * EK;  // row 1

    char* p = (char*)d_ws;
    auto take = [&](size_t bytes) -> void* {
        void* q = (void*)p;
        p += (bytes + 255) & ~(size_t)255;
        return q;
    };
    int*          cnt   = (int*)         take((size_t)KK * NN * 4);
    float*        dinv  = (float*)       take((size_t)KK * NN * 4);
    unsigned int* colw  = (unsigned int*)take((size_t)KK * NN * CAP * 4 + 128);
    float*        Wt    = (float*)       take((size_t)15 * HIDD * HIDD * 4);
    float*        embWt = (float*)       take((size_t)INDIM * HIDD * 4);
    half_t*       xh    = (half_t*)      take((size_t)6 * NN * HIDD * 2);

    hipMemsetAsync(cnt, 0, (size_t)KK * NN * 4, stream);

    int etotal = KK * EK;
    k_scatter<<<(etotal + 255) / 256, 256, 0, stream>>>(srcA, dstA, cnt, colw);
    k_dinv<<<(KK * NN + 255) / 256, 256, 0, stream>>>(cnt, dinv);
    k_edgew<<<(KK * NN + 255) / 256, 256, 0, stream>>>(cnt, dinv, colw);

    k_tr<<<(15 * HIDD * HIDD + 255) / 256, 256, 0, stream>>>(conv_W, Wt, HIDD, HIDD,
                                                             15 * HIDD * HIDD);
    k_tr<<<(HIDD * INDIM + 255) / 256, 256, 0, stream>>>(emb_W, embWt, HIDD, INDIM,
                                                         HIDD * INDIM);

    k_emb<<<NB, 256, 0, stream>>>(x, embWt, emb_b, xh);

    for (int l = 0; l < 5; ++l) {
        k_layer<<<NB, 512, 0, stream>>>(
            xh, cnt, colw, dinv, Wt, conv_b, l + 1,
            xh + (size_t)(l + 1) * NN * HIDD);
    }

    k_poolf<<<GG, 256, 0, stream>>>(xh + (size_t)5 * NN * HIDD, r1W, r1b, r2W, r2b,
                                    (float*)d_out);
}

// Round 22
// 1110.427 us; speedup vs baseline: 1.0456x; 1.0456x over previous
//
#include <hip/hip_runtime.h>
#include <cstdint>
#include <cstddef>

#define NN 50000
#define INDIM 32
#define HIDD 128
#define OUTD 10
#define KK 5
#define EK 400000
#define GG 500
#define CAP 40   // max node degree per slice; Poisson(mean 8) -> overflow ~1e-15
#define NB 782   // (NN+63)/64 row tiles

typedef __attribute__((ext_vector_type(4))) float float4v;
typedef __attribute__((ext_vector_type(4))) unsigned short ushort4v;
typedef unsigned short ushort;
typedef _Float16 half_t;
typedef __attribute__((ext_vector_type(4))) _Float16 half4v;
typedef __attribute__((ext_vector_type(8))) _Float16 half8v;

// ---------- fused degree-count + capacity-CSR scatter (ushort col) ----------
__global__ void k_scatter(const int* __restrict__ srcA, const int* __restrict__ dstA,
                          int* __restrict__ cnt, ushort* __restrict__ col) {
    int e = blockIdx.x * blockDim.x + threadIdx.x;
    if (e >= KK * EK) return;
    int s = e / EK;
    int sv = srcA[e], dv = dstA[e];
    int pos = atomicAdd(&cnt[s * NN + dv], 1);
    if (pos < CAP) col[(size_t)(s * NN + dv) * CAP + pos] = (ushort)sv;
}

// dinv = 1/sqrt(deg+1)
__global__ void k_dinv(const int* __restrict__ cnt, float* __restrict__ dinv) {
    int i = blockIdx.x * blockDim.x + threadIdx.x;
    if (i >= KK * NN) return;
    float d = (float)(cnt[i] + 1);
    dinv[i] = 1.0f / sqrtf(d);
}

// ---------- weight transpose: in[m][j][c] -> out[m][c][j] ----------
__global__ void k_tr(const float* __restrict__ in, float* __restrict__ out,
                     int J, int C, int total) {
    int idx = blockIdx.x * blockDim.x + threadIdx.x;
    if (idx >= total) return;
    int jc = J * C;
    int m = idx / jc, rem = idx - m * jc;
    int j = rem / C, c = rem - j * C;
    out[m * jc + c * J + j] = in[idx];
}

// ---------- fused layer, 512-thread blocks, fp16 activations ----------------
// Gather reads fp16 rows (256B = 4 lines/edge, halves L2-miss bytes);
// all accumulation / LDS / GEMM stay fp32; epilogue re-quantizes to fp16.
__global__ __launch_bounds__(512) void k_layer(const half_t* __restrict__ xh,
                                               const int* __restrict__ cnt,
                                               const ushort* __restrict__ col,
                                               const float* __restrict__ dinv,
                                               const float* __restrict__ Wt,
                                               const float* __restrict__ conv_b,
                                               int lp1, half_t* __restrict__ out) {
    constexpr int LDA = HIDD + 4;  // 132 words: 16B-aligned stage writes, pad
    __shared__ float At[64 * LDA];
    const int tid = threadIdx.x;
    const int r0 = blockIdx.x * 64;
    const int lane = tid & 63, wv = tid >> 6;        // wv in [0,8)
    const int half = lane >> 5, ln = lane & 31;
    const int hw = wv * 2 + half;                    // half-wave id in [0,16)
    const int tr = tid >> 5, tc = tid & 31;          // GEMM: 16 row-groups x 32 cols
    const int ra = tr * 4;
    const int cib = (lp1 - 1) * lp1 / 2;

    float acc[4][4];
#pragma unroll
    for (int q = 0; q < 4; ++q)
#pragma unroll
        for (int u = 0; u < 4; ++u) acc[q][u] = 0.f;

    for (int k = 1; k <= lp1; ++k) {
        const int s = k - 1, sN = s * NN, ci = cib + s;
        const float inv_k = 1.0f / (float)k;
        const half_t* Xin = xh + (size_t)(lp1 - k) * NN * HIDD;
        const float* dvs = dinv + sN;

        // ---- gather phase: 16 half-waves x 4 passes cover 64 rows ----
#pragma unroll 1
        for (int pass = 0; pass < 4; ++pass) {
            int lrow = pass * 16 + hw;
            int node = r0 + lrow;
            bool valid = node < NN;
            int nc = valid ? node : NN - 1;
            int cn = 0;
            if (valid) {
                cn = cnt[sN + node];
                cn = cn < CAP ? cn : CAP;
            }
            const ushort* cp = col + (size_t)(sN + nc) * CAP;
            float dv = valid ? dvs[node] : 0.f;
            float hd = dv * inv_k;   // row coef; 0 for invalid rows kills garbage
            const half_t* Xb = Xin + ln * 4;
            // self term: (dinv^2/k)*x_v  ==  (x_v*dv)*hd
            float4v a = __builtin_convertvector(
                            *(const half4v*)(Xb + (size_t)nc * HIDD), float4v) * dv;

            int cnr = (cn + 3) & ~3;
            int cm = cnr;
            {   // shared instruction stream: bound = max over the wave's two halves
                int o = __shfl_xor(cnr, 32);
                cm = cm > o ? cm : o;
            }
            ushort4v cc = *(const ushort4v*)(cp);
            for (int i = 0; i < cm; i += 4) {
                ushort4v ccn = *(const ushort4v*)(cp + i + 4);  // prefetch next
                int j0 = (i + 0 < cn) ? (int)cc.x : nc;
                int j1 = (i + 1 < cn) ? (int)cc.y : nc;
                int j2 = (i + 2 < cn) ? (int)cc.z : nc;
                int j3 = (i + 3 < cn) ? (int)cc.w : nc;
                half4v h0 = *(const half4v*)(Xb + (size_t)j0 * HIDD);
                half4v h1 = *(const half4v*)(Xb + (size_t)j1 * HIDD);
                half4v h2 = *(const half4v*)(Xb + (size_t)j2 * HIDD);
                half4v h3 = *(const half4v*)(Xb + (size_t)j3 * HIDD);
                float w0 = dvs[j0];
                float w1 = dvs[j1];
                float w2 = dvs[j2];
                float w3 = dvs[j3];
                if (i + 0 >= cn) w0 = 0.f;
                if (i + 1 >= cn) w1 = 0.f;
                if (i + 2 >= cn) w2 = 0.f;
                if (i + 3 >= cn) w3 = 0.f;
                a += __builtin_convertvector(h0, float4v) * w0
                   + __builtin_convertvector(h1, float4v) * w1
                   + __builtin_convertvector(h2, float4v) * w2
                   + __builtin_convertvector(h3, float4v) * w3;
                cc = ccn;
            }
            *(float4v*)(&At[lrow * LDA + ln * 4]) = a * hd;
        }
        __syncthreads();

        // ---- GEMM phase: acc += At @ Wt[ci]; per thread: 4 rows x 4 cols ----
        const float* wp = Wt + (size_t)ci * HIDD * HIDD + tc * 4;
#pragma unroll 4
        for (int c = 0; c < HIDD; ++c) {
            float4v w0 = *(const float4v*)(wp + (size_t)c * HIDD);
            float a0 = At[(ra + 0) * LDA + c];
            float a1 = At[(ra + 1) * LDA + c];
            float a2 = At[(ra + 2) * LDA + c];
            float a3 = At[(ra + 3) * LDA + c];
#pragma unroll
            for (int u = 0; u < 4; ++u) {
                acc[0][u] += a0 * w0[u];
                acc[1][u] += a1 * w0[u];
                acc[2][u] += a2 * w0[u];
                acc[3][u] += a3 * w0[u];
            }
        }
        __syncthreads();   // before next k's gather overwrites At
    }

    // ---- epilogue: summed bias, relu, quantize to fp16, single write ----
    float bj[4];
#pragma unroll
    for (int u = 0; u < 4; ++u) bj[u] = 0.f;
    for (int k = 1; k <= lp1; ++k) {
        const float* bp = conv_b + (size_t)(cib + k - 1) * HIDD + tc * 4;
        float inv_k = 1.0f / (float)k;
#pragma unroll
        for (int u = 0; u < 4; ++u) bj[u] += bp[u] * inv_k;
    }
#pragma unroll
    for (int q = 0; q < 4; ++q) {
        int gr = r0 + ra + q;
        if (gr >= NN) continue;
        half_t* op = out + (size_t)gr * HIDD + tc * 4;
        half4v o0;
#pragma unroll
        for (int u = 0; u < 4; ++u) {
            float v = acc[q][u] + bj[u];
            o0[u] = (half_t)(v > 0.f ? v : 0.f);
        }
        *(half4v*)(op) = o0;
    }
}

// ---------- embedding GEMM (K=32): xh0 = fp16( x @ emb_W.T + emb_b ) --------
__global__ __launch_bounds__(256) void k_emb(const float* __restrict__ A,
                                             const float* __restrict__ Wt,
                                             const float* __restrict__ bias,
                                             half_t* __restrict__ out) {
    constexpr int KD = INDIM, LDA = KD + 4;
    __shared__ float At[64 * LDA];
    int tid = threadIdx.x;
    int r0 = blockIdx.x * 64;

    constexpr int F4R = KD / 4;
    constexpr int PER = 64 * F4R / 256;
#pragma unroll
    for (int t = 0; t < PER; ++t) {
        int f4 = tid + t * 256;
        int row = f4 / F4R, c4 = (f4 - row * F4R) * 4;
        float4v v = {0.f, 0.f, 0.f, 0.f};
        int gr = r0 + row;
        if (gr < NN) v = *(const float4v*)(A + (size_t)gr * KD + c4);
        *(float4v*)(At + row * LDA + c4) = v;
    }
    __syncthreads();

    int tr = tid >> 4, tc = tid & 15;
    int ra = tr * 4;
    float acc[4][8];
#pragma unroll
    for (int q = 0; q < 4; ++q)
#pragma unroll
        for (int u = 0; u < 8; ++u) acc[q][u] = 0.f;

    const float* wp = Wt + tc * 8;
#pragma unroll
    for (int c = 0; c < KD; ++c) {
        float4v w0 = *(const float4v*)(wp + (size_t)c * HIDD);
        float4v w1 = *(const float4v*)(wp + (size_t)c * HIDD + 4);
        float a0 = At[(ra + 0) * LDA + c];
        float a1 = At[(ra + 1) * LDA + c];
        float a2 = At[(ra + 2) * LDA + c];
        float a3 = At[(ra + 3) * LDA + c];
#pragma unroll
        for (int u = 0; u < 4; ++u) {
            acc[0][u] += a0 * w0[u];  acc[0][u + 4] += a0 * w1[u];
            acc[1][u] += a1 * w0[u];  acc[1][u + 4] += a1 * w1[u];
            acc[2][u] += a2 * w0[u];  acc[2][u + 4] += a2 * w1[u];
            acc[3][u] += a3 * w0[u];  acc[3][u + 4] += a3 * w1[u];
        }
    }

#pragma unroll
    for (int q = 0; q < 4; ++q) {
        int gr = r0 + ra + q;
        if (gr >= NN) continue;
        half_t* op = out + (size_t)gr * HIDD + tc * 8;
        half8v o;
#pragma unroll
        for (int u = 0; u < 8; ++u)
            o[u] = (half_t)(acc[q][u] + bias[tc * 8 + u]);
        *(half8v*)(op) = o;
    }
}

// ---------- pooling (100 consecutive nodes/graph, fp16 in) + 2-layer MLP ----
__global__ __launch_bounds__(256) void k_poolf(const half_t* __restrict__ h,
                                               const float* __restrict__ r1W,
                                               const float* __restrict__ r1b,
                                               const float* __restrict__ r2W,
                                               const float* __restrict__ r2b,
                                               float* __restrict__ out) {
    __shared__ float pooled[384];
    __shared__ float hid[192];
    int g = blockIdx.x, tid = threadIdx.x;
    if (tid < 128) {
        const half_t* hp = h + (size_t)g * 100 * HIDD + tid;
        float s = 0.f, m = -3.0e38f;
        for (int n = 0; n < 100; ++n) {
            float v = (float)hp[(size_t)n * HIDD];
            s += v;
            m = fmaxf(m, v);
        }
        pooled[tid] = s;
        pooled[128 + tid] = m;
        pooled[256 + tid] = s * 0.01f;
    }
    __syncthreads();
    if (tid < 192) {
        float acc = r1b[tid];
        const float* w = r1W + (size_t)tid * 384;
        for (int c = 0; c < 384; ++c) acc += pooled[c] * w[c];
        hid[tid] = acc >= 0.f ? acc : 0.01f * acc;
    }
    __syncthreads();
    if (tid < OUTD) {
        float acc = r2b[tid];
        const float* w = r2W + (size_t)tid * 192;
        for (int c = 0; c < 192; ++c) acc += hid[c] * w[c];
        out[g * OUTD + tid] = acc;
    }
}

extern "C" void kernel_launch(void* const* d_in, const int* in_sizes, int n_in,
                              void* d_out, int out_size, void* d_ws, size_t ws_size,
                              hipStream_t stream) {
    const float* x      = (const float*)d_in[0];
    const int*   kei    = (const int*)d_in[1];
    const float* emb_W  = (const float*)d_in[4];
    const float* emb_b  = (const float*)d_in[5];
    const float* conv_W = (const float*)d_in[6];
    const float* conv_b = (const float*)d_in[7];
    const float* r1W    = (const float*)d_in[8];
    const float* r1b    = (const float*)d_in[9];
    const float* r2W    = (const float*)d_in[10];
    const float* r2b    = (const float*)d_in[11];

    const int* srcA = kei;            // row 0 of (2, K*E_K)
    const int* dstA = kei + KK * EK;  // row 1

    char* p = (char*)d_ws;
    auto take = [&](size_t bytes) -> void* {
        void* q = (void*)p;
        p += (bytes + 255) & ~(size_t)255;
        return q;
    };
    int*    cnt    = (int*)   take((size_t)KK * NN * 4);
    float*  dinv   = (float*) take((size_t)KK * NN * 4);
    ushort* col    = (ushort*)take((size_t)KK * NN * CAP * 2 + 128);  // +slack for prefetch
    float*  Wt     = (float*) take((size_t)15 * HIDD * HIDD * 4);
    float*  embWt  = (float*) take((size_t)INDIM * HIDD * 4);
    half_t* xh     = (half_t*)take((size_t)6 * NN * HIDD * 2);  // fp16 activations

    hipMemsetAsync(cnt, 0, (size_t)KK * NN * 4, stream);

    int etotal = KK * EK;
    k_scatter<<<(etotal + 255) / 256, 256, 0, stream>>>(srcA, dstA, cnt, col);
    k_dinv<<<(KK * NN + 255) / 256, 256, 0, stream>>>(cnt, dinv);

    k_tr<<<(15 * HIDD * HIDD + 255) / 256, 256, 0, stream>>>(conv_W, Wt, HIDD, HIDD,
                                                             15 * HIDD * HIDD);
    k_tr<<<(HIDD * INDIM + 255) / 256, 256, 0, stream>>>(emb_W, embWt, HIDD, INDIM,
                                                         HIDD * INDIM);

    k_emb<<<NB, 256, 0, stream>>>(x, embWt, emb_b, xh);

    for (int l = 0; l < 5; ++l) {
        k_layer<<<NB, 512, 0, stream>>>(
            xh, cnt, col, dinv, Wt, conv_b, l + 1,
            xh + (size_t)(l + 1) * NN * HIDD);
    }

    k_poolf<<<GG, 256, 0, stream>>>(xh + (size_t)5 * NN * HIDD, r1W, r1b, r2W, r2b,
                                    (float*)d_out);
}